// Round 1
// baseline (284.901 us; speedup 1.0000x reference)
//
#include <hip/hip_runtime.h>

typedef short short8 __attribute__((ext_vector_type(8)));
typedef short short4v __attribute__((ext_vector_type(4)));
typedef float f32x4 __attribute__((ext_vector_type(4)));

#define NB 4
#define CD 256
#define ID 128
#define NP 4096

static __device__ __forceinline__ short f2bf(float f){
  unsigned u = __float_as_uint(f);
  u += 0x7FFF + ((u >> 16) & 1);
  return (short)(u >> 16);
}

// ---------------- weights fp32 -> bf16 (g, theta, phi, out concatenated) ----
__global__ __launch_bounds__(256) void k_cvtw(const float* __restrict__ g_w,
    const float* __restrict__ th_w, const float* __restrict__ ph_w,
    const float* __restrict__ out_w, short* __restrict__ wb){
  int idx = (blockIdx.x * 256 + threadIdx.x) * 4;
  const float* s;
  int sel = idx >> 15;
  if(sel == 0) s = g_w; else if(sel == 1) s = th_w; else if(sel == 2) s = ph_w; else s = out_w;
  int off = idx & 32767;
  float4 v = *reinterpret_cast<const float4*>(s + off);
  short4v o = { f2bf(v.x), f2bf(v.y), f2bf(v.z), f2bf(v.w) };
  *reinterpret_cast<short4v*>(wb + idx) = o;
}

// ---------------- x (n,C,N) fp32 -> xt (n,N,C) bf16 -------------------------
__global__ __launch_bounds__(256) void k_transpose(const float* __restrict__ x,
                                                   short* __restrict__ xt){
  __shared__ float T[64][68];
  int n = blockIdx.z, c0 = blockIdx.y * 64, p0 = blockIdx.x * 64;
  int t = threadIdx.x;
  const float* xp = x + ((size_t)(n * CD + c0)) * NP + p0;
#pragma unroll
  for(int it = 0; it < 4; ++it){
    int c = (t >> 4) + it * 16;
    int p = (t & 15) * 4;
    float4 v = *reinterpret_cast<const float4*>(xp + (size_t)c * NP + p);
    T[c][p+0] = v.x; T[c][p+1] = v.y; T[c][p+2] = v.z; T[c][p+3] = v.w;
  }
  __syncthreads();
  short* op = xt + ((size_t)(n * NP + p0)) * CD + c0;
  int p = t >> 2, cc = (t & 3) * 16;
  short8 a, b;
#pragma unroll
  for(int j = 0; j < 8; ++j){ a[j] = f2bf(T[cc + j][p]); b[j] = f2bf(T[cc + 8 + j][p]); }
  *reinterpret_cast<short8*>(op + (size_t)p * CD + cc) = a;
  *reinterpret_cast<short8*>(op + (size_t)p * CD + cc + 8) = b;
}

// ---------------- projections: theta/phi -> (n,N,I); g -> (n,I,N) -----------
__global__ __launch_bounds__(256) void k_proj(const short* __restrict__ xt,
    const short* __restrict__ wb, const float* __restrict__ g_b,
    const float* __restrict__ th_b, const float* __restrict__ ph_b,
    short* __restrict__ q_ws, short* __restrict__ k_ws, short* __restrict__ v_ws){
  int bid = blockIdx.x;
  int t = threadIdx.x, w = t >> 6, l = t & 63;
  int lr = l & 15, lg = l >> 4, koff = lg * 8;
  if(bid < 256){
    // mode A: theta + phi, out (N,I); A = xt rows (p), B = W^T
    int n = bid >> 6, p0 = (bid & 63) << 6;
    const short* th_wb = wb + 32768;
    const short* ph_wb = wb + 65536;
    int pr = p0 + w * 16 + lr;
    const short* arow = xt + ((size_t)(n * NP + pr)) * CD;
    short8 A[8];
#pragma unroll
    for(int kk = 0; kk < 8; ++kk) A[kk] = *reinterpret_cast<const short8*>(arow + kk * 32 + koff);
    f32x4 accT[8], accP[8];
#pragma unroll
    for(int nf = 0; nf < 8; ++nf){ accT[nf] = {0.f,0.f,0.f,0.f}; accP[nf] = {0.f,0.f,0.f,0.f}; }
#pragma unroll
    for(int kk = 0; kk < 8; ++kk){
#pragma unroll
      for(int nf = 0; nf < 8; ++nf){
        int i = nf * 16 + lr;
        short8 Bt = *reinterpret_cast<const short8*>(th_wb + (size_t)i * CD + kk * 32 + koff);
        short8 Bp = *reinterpret_cast<const short8*>(ph_wb + (size_t)i * CD + kk * 32 + koff);
        accT[nf] = __builtin_amdgcn_mfma_f32_16x16x32_bf16(A[kk], Bt, accT[nf], 0, 0, 0);
        accP[nf] = __builtin_amdgcn_mfma_f32_16x16x32_bf16(A[kk], Bp, accP[nf], 0, 0, 0);
      }
    }
    int prow = p0 + w * 16 + lg * 4;
#pragma unroll
    for(int nf = 0; nf < 8; ++nf){
      int i = nf * 16 + lr;
      float bt = th_b[i], bp = ph_b[i];
#pragma unroll
      for(int r = 0; r < 4; ++r){
        size_t o = ((size_t)(n * NP + prow + r)) * ID + i;
        q_ws[o] = f2bf(accT[nf][r] + bt);
        k_ws[o] = f2bf(accP[nf][r] + bp);
      }
    }
  } else {
    // mode B: g, out (I,N); A = g_w rows (i), B = xt^T columns
    int b2 = bid - 256;
    int n = b2 >> 6, p0 = (b2 & 63) << 6;
    const short* g_wb = wb;
    int ib = w * 32;
    f32x4 acc[2][4];
#pragma unroll
    for(int mf = 0; mf < 2; ++mf)
#pragma unroll
      for(int nf = 0; nf < 4; ++nf) acc[mf][nf] = {0.f,0.f,0.f,0.f};
#pragma unroll
    for(int kk = 0; kk < 8; ++kk){
      short8 Af[2];
#pragma unroll
      for(int mf = 0; mf < 2; ++mf)
        Af[mf] = *reinterpret_cast<const short8*>(g_wb + (size_t)(ib + mf * 16 + lr) * CD + kk * 32 + koff);
#pragma unroll
      for(int nf = 0; nf < 4; ++nf){
        int p = p0 + nf * 16 + lr;
        short8 B = *reinterpret_cast<const short8*>(xt + ((size_t)(n * NP + p)) * CD + kk * 32 + koff);
        acc[0][nf] = __builtin_amdgcn_mfma_f32_16x16x32_bf16(Af[0], B, acc[0][nf], 0, 0, 0);
        acc[1][nf] = __builtin_amdgcn_mfma_f32_16x16x32_bf16(Af[1], B, acc[1][nf], 0, 0, 0);
      }
    }
#pragma unroll
    for(int mf = 0; mf < 2; ++mf){
      int i0 = ib + mf * 16 + lg * 4;
#pragma unroll
      for(int nf = 0; nf < 4; ++nf){
        int p = p0 + nf * 16 + lr;
#pragma unroll
        for(int r = 0; r < 4; ++r){
          v_ws[((size_t)(n * ID + i0 + r)) * NP + p] = f2bf(acc[mf][nf][r] + g_b[i0 + r]);
        }
      }
    }
  }
}

// ---------------- flash attention: softmax(Q K^T)/16 @ V --------------------
__global__ __launch_bounds__(256) void k_attn(const short* __restrict__ q_ws,
    const short* __restrict__ k_ws, const short* __restrict__ v_ws,
    short* __restrict__ o_ws){
  __shared__ __align__(16) short Pl[4][16 * 72];
  __shared__ float Mrg[2][16][128];
  __shared__ float Msc[2][16][2];
  int b = blockIdx.x;
  int n = b >> 7, p0 = (b & 127) << 5;
  int t = threadIdx.x, w = t >> 6, l = t & 63;
  int lr = l & 15, lg = l >> 4, koff = lg * 8;
  int qw = w & 1, kh = w >> 1;
  const short* qrow = q_ws + ((size_t)(n * NP + p0 + qw * 16 + lr)) * ID;
  short8 Qf[4];
#pragma unroll
  for(int kk = 0; kk < 4; ++kk) Qf[kk] = *reinterpret_cast<const short8*>(qrow + kk * 32 + koff);
  f32x4 Of[8];
#pragma unroll
  for(int nf = 0; nf < 8; ++nf) Of[nf] = {0.f,0.f,0.f,0.f};
  float m[4], lsum[4];
#pragma unroll
  for(int r = 0; r < 4; ++r){ m[r] = -3e38f; lsum[r] = 0.f; }
  const short* kbase = k_ws + (size_t)n * NP * ID;
  const short* vbase = v_ws + (size_t)n * ID * NP;
  short* pw = &Pl[w][0];
  for(int kt = 0; kt < 32; ++kt){
    int kb = kh * 2048 + kt * 64;
    f32x4 S[4];
#pragma unroll
    for(int nf = 0; nf < 4; ++nf) S[nf] = {0.f,0.f,0.f,0.f};
#pragma unroll
    for(int kk = 0; kk < 4; ++kk){
#pragma unroll
      for(int nf = 0; nf < 4; ++nf){
        short8 B = *reinterpret_cast<const short8*>(kbase + (size_t)(kb + nf * 16 + lr) * ID + kk * 32 + koff);
        S[nf] = __builtin_amdgcn_mfma_f32_16x16x32_bf16(Qf[kk], B, S[nf], 0, 0, 0);
      }
    }
#pragma unroll
    for(int r = 0; r < 4; ++r){
      float v = fmaxf(fmaxf(S[0][r], S[1][r]), fmaxf(S[2][r], S[3][r]));
      v = fmaxf(v, __shfl_xor(v, 1));
      v = fmaxf(v, __shfl_xor(v, 2));
      v = fmaxf(v, __shfl_xor(v, 4));
      v = fmaxf(v, __shfl_xor(v, 8));
      float mn = fmaxf(m[r], v);
      float al = __expf(m[r] - mn);
      m[r] = mn;
      float s0 = 0.f;
#pragma unroll
      for(int nf = 0; nf < 4; ++nf){
        float e = __expf(S[nf][r] - mn);
        S[nf][r] = e;
        s0 += e;
      }
      s0 += __shfl_xor(s0, 1);
      s0 += __shfl_xor(s0, 2);
      s0 += __shfl_xor(s0, 4);
      s0 += __shfl_xor(s0, 8);
      lsum[r] = lsum[r] * al + s0;
#pragma unroll
      for(int nf = 0; nf < 8; ++nf) Of[nf][r] *= al;
    }
    // P tile -> LDS (per-wave private, padded stride 72)
#pragma unroll
    for(int nf = 0; nf < 4; ++nf){
#pragma unroll
      for(int r = 0; r < 4; ++r){
        pw[(lg * 4 + r) * 72 + nf * 16 + lr] = f2bf(S[nf][r]);
      }
    }
    asm volatile("s_waitcnt lgkmcnt(0)" ::: "memory");
#pragma unroll
    for(int kk2 = 0; kk2 < 2; ++kk2){
      short8 Ap = *reinterpret_cast<const short8*>(pw + lr * 72 + kk2 * 32 + koff);
#pragma unroll
      for(int nf = 0; nf < 8; ++nf){
        short8 Bv = *reinterpret_cast<const short8*>(vbase + (size_t)(nf * 16 + lr) * NP + kb + kk2 * 32 + koff);
        Of[nf] = __builtin_amdgcn_mfma_f32_16x16x32_bf16(Ap, Bv, Of[nf], 0, 0, 0);
      }
    }
  }
  // merge the two k-halves (waves kh=1 publish, kh=0 combine + store)
  if(kh == 1){
#pragma unroll
    for(int nf = 0; nf < 8; ++nf){
      int col = nf * 16 + lr;
#pragma unroll
      for(int r = 0; r < 4; ++r) Mrg[qw][lg * 4 + r][col] = Of[nf][r];
    }
    if(lr == 0){
#pragma unroll
      for(int r = 0; r < 4; ++r){ Msc[qw][lg * 4 + r][0] = m[r]; Msc[qw][lg * 4 + r][1] = lsum[r]; }
    }
  }
  __syncthreads();
  if(kh == 0){
    float sc1[4], sc2[4];
#pragma unroll
    for(int r = 0; r < 4; ++r){
      int row = lg * 4 + r;
      float m2 = Msc[qw][row][0], l2 = Msc[qw][row][1];
      float mm = fmaxf(m[r], m2);
      float e1 = __expf(m[r] - mm), e2 = __expf(m2 - mm);
      float inv = 1.f / (16.f * (lsum[r] * e1 + l2 * e2));   // 1/16 = 1/sqrt(C) folded here
      sc1[r] = e1 * inv; sc2[r] = e2 * inv;
    }
    short* orow = o_ws + ((size_t)(n * NP + p0 + qw * 16)) * ID;
#pragma unroll
    for(int nf = 0; nf < 8; ++nf){
      int col = nf * 16 + lr;
#pragma unroll
      for(int r = 0; r < 4; ++r){
        int row = lg * 4 + r;
        orow[(size_t)row * ID + col] = f2bf(Of[nf][r] * sc1[r] + Mrg[qw][row][col] * sc2[r]);
      }
    }
  }
}

// ---------------- out 1x1 conv + BN + residual ------------------------------
__global__ __launch_bounds__(256) void k_outproj(const short* __restrict__ o_ws,
    const short* __restrict__ ow_b, const float* __restrict__ bng,
    const float* __restrict__ bnb, const float* __restrict__ bnm,
    const float* __restrict__ bnv, const float* __restrict__ x,
    float* __restrict__ out){
  int b = blockIdx.x;
  int n = b >> 6, c0 = ((b >> 4) & 3) << 6, pb = (b & 15) << 8;
  int t = threadIdx.x, w = t >> 6, l = t & 63;
  int lr = l & 15, lg = l >> 4, koff = lg * 8;
  int p0 = pb + w * 64;
  f32x4 acc[4][4];
#pragma unroll
  for(int mf = 0; mf < 4; ++mf)
#pragma unroll
    for(int nf = 0; nf < 4; ++nf) acc[mf][nf] = {0.f,0.f,0.f,0.f};
#pragma unroll
  for(int kk = 0; kk < 4; ++kk){
    short8 Af[4];
#pragma unroll
    for(int mf = 0; mf < 4; ++mf)
      Af[mf] = *reinterpret_cast<const short8*>(ow_b + (size_t)(c0 + mf * 16 + lr) * ID + kk * 32 + koff);
#pragma unroll
    for(int nf = 0; nf < 4; ++nf){
      short8 Bf = *reinterpret_cast<const short8*>(o_ws + ((size_t)(n * NP + p0 + nf * 16 + lr)) * ID + kk * 32 + koff);
#pragma unroll
      for(int mf = 0; mf < 4; ++mf)
        acc[mf][nf] = __builtin_amdgcn_mfma_f32_16x16x32_bf16(Af[mf], Bf, acc[mf][nf], 0, 0, 0);
    }
  }
#pragma unroll
  for(int mf = 0; mf < 4; ++mf){
    int cb = c0 + mf * 16 + lg * 4;
    float inv[4], sh[4];
#pragma unroll
    for(int r = 0; r < 4; ++r){
      float iv = bng[cb + r] * rsqrtf(bnv[cb + r] + 1e-5f);
      inv[r] = iv;
      sh[r] = bnb[cb + r] - bnm[cb + r] * iv;
    }
#pragma unroll
    for(int nf = 0; nf < 4; ++nf){
      int p = p0 + nf * 16 + lr;
#pragma unroll
      for(int r = 0; r < 4; ++r){
        size_t idx = ((size_t)(n * CD + cb + r)) * NP + p;
        out[idx] = acc[mf][nf][r] * inv[r] + sh[r] + x[idx];
      }
    }
  }
}

extern "C" void kernel_launch(void* const* d_in, const int* in_sizes, int n_in,
                              void* d_out, int out_size, void* d_ws, size_t ws_size,
                              hipStream_t stream){
  const float* x    = (const float*)d_in[0];
  const float* g_w  = (const float*)d_in[1];
  const float* g_b  = (const float*)d_in[2];
  const float* th_w = (const float*)d_in[3];
  const float* th_b = (const float*)d_in[4];
  const float* ph_w = (const float*)d_in[5];
  const float* ph_b = (const float*)d_in[6];
  const float* out_w= (const float*)d_in[7];
  const float* bng  = (const float*)d_in[8];
  const float* bnb  = (const float*)d_in[9];
  const float* bnm  = (const float*)d_in[10];
  const float* bnv  = (const float*)d_in[11];
  float* out = (float*)d_out;
  char* ws = (char*)d_ws;

  short* xt   = (short*)(ws);                       // 8 MB  (n,N,C) bf16
  short* q_ws = (short*)(ws + (size_t)(8u  << 20)); // 4 MB  (n,N,I)
  short* k_ws = (short*)(ws + (size_t)(12u << 20)); // 4 MB  (n,N,I)
  short* v_ws = (short*)(ws + (size_t)(16u << 20)); // 4 MB  (n,I,N)
  short* o_ws = (short*)(ws + (size_t)(20u << 20)); // 4 MB  (n,N,I)
  short* wb   = (short*)(ws + (size_t)(24u << 20)); // 256 KB bf16 weights

  k_cvtw<<<128, 256, 0, stream>>>(g_w, th_w, ph_w, out_w, wb);
  k_transpose<<<dim3(64, 4, 4), 256, 0, stream>>>(x, xt);
  k_proj<<<512, 256, 0, stream>>>(xt, wb, g_b, th_b, ph_b, q_ws, k_ws, v_ws);
  k_attn<<<512, 256, 0, stream>>>(q_ws, k_ws, v_ws, o_ws);
  k_outproj<<<256, 256, 0, stream>>>(o_ws, wb + 98304, bng, bnb, bnm, bnv, x, out);
}